// Round 1
// baseline (3388.734 us; speedup 1.0000x reference)
//
#include <hip/hip_runtime.h>
#include <hip/hip_bf16.h>

#define B_   128
#define S_   128
#define IN_  512
#define H_   256
#define G3_  768   // 3*H
#define C_   256
#define D2H_ 512   // 2*H

// ---------------------------------------------------------------------------
// K1: xp = x @ [w_ih_f; w_ih_b]^T + b_ih  (both directions in one GEMM)
// A: [M=16384, K=512], row m = b*128+s. N = 1536 (cols 0..767 fwd, 768..1535 bwd)
// Store: xpf[t=s][b][g], xpb[t=127-s][b][g]  (time reversal folded into store)
// ---------------------------------------------------------------------------
__global__ __launch_bounds__(256) void xp_gemm(
    const float* __restrict__ x,
    const float* __restrict__ wf, const float* __restrict__ wb,
    const float* __restrict__ bf, const float* __restrict__ bb,
    float* __restrict__ xpf, float* __restrict__ xpb)
{
  const int bm = blockIdx.x;          // 0..255
  const int n0 = blockIdx.y * 64;     // 0..1472
  const bool fwd = (n0 < G3_);
  const float* __restrict__ w    = fwd ? wf : wb;
  const float* __restrict__ bias = fwd ? bf : bb;
  const int nc0 = fwd ? n0 : (n0 - G3_);

  __shared__ float As[16][68];        // [k][m], pad 68 keeps 16B align, 2-way max
  __shared__ float Bs[16][68];        // [k][n]

  const int tid = threadIdx.x;
  const int row = tid >> 2;           // 0..63
  const int kq  = (tid & 3) << 2;     // 0,4,8,12
  const int tx  = tid & 15, ty = tid >> 4;

  const float* arow = x + (size_t)(bm * 64 + row) * IN_ + kq;
  const float* brow = w + (size_t)(nc0 + row) * IN_ + kq;

  float acc[4][4] = {};

  for (int k0 = 0; k0 < IN_; k0 += 16) {
    float4 av = *(const float4*)(arow + k0);
    float4 bv = *(const float4*)(brow + k0);
    As[kq + 0][row] = av.x; As[kq + 1][row] = av.y;
    As[kq + 2][row] = av.z; As[kq + 3][row] = av.w;
    Bs[kq + 0][row] = bv.x; Bs[kq + 1][row] = bv.y;
    Bs[kq + 2][row] = bv.z; Bs[kq + 3][row] = bv.w;
    __syncthreads();
#pragma unroll
    for (int k = 0; k < 16; ++k) {
      float4 a = *(const float4*)&As[k][ty * 4];
      float4 b = *(const float4*)&Bs[k][tx * 4];
      acc[0][0] += a.x * b.x; acc[0][1] += a.x * b.y; acc[0][2] += a.x * b.z; acc[0][3] += a.x * b.w;
      acc[1][0] += a.y * b.x; acc[1][1] += a.y * b.y; acc[1][2] += a.y * b.z; acc[1][3] += a.y * b.w;
      acc[2][0] += a.z * b.x; acc[2][1] += a.z * b.y; acc[2][2] += a.z * b.z; acc[2][3] += a.z * b.w;
      acc[3][0] += a.w * b.x; acc[3][1] += a.w * b.y; acc[3][2] += a.w * b.z; acc[3][3] += a.w * b.w;
    }
    __syncthreads();
  }

  float4 bv4 = *(const float4*)(bias + nc0 + tx * 4);
#pragma unroll
  for (int i = 0; i < 4; ++i) {
    int m = bm * 64 + ty * 4 + i;
    int b = m >> 7, s = m & 127;
    float4 o;
    o.x = acc[i][0] + bv4.x; o.y = acc[i][1] + bv4.y;
    o.z = acc[i][2] + bv4.z; o.w = acc[i][3] + bv4.w;
    if (fwd)
      *(float4*)(xpf + ((size_t)s * B_ + b) * G3_ + nc0 + tx * 4) = o;
    else
      *(float4*)(xpb + ((size_t)(S_ - 1 - s) * B_ + b) * G3_ + nc0 + tx * 4) = o;
  }
}

// ---------------------------------------------------------------------------
// K2: bidirectional GRU recurrence. 64 blocks = 2 dirs x 32 groups of 4 batches.
// Thread tid owns hidden unit tid (rows tid, 256+tid, 512+tid of w_hh).
// h lives in LDS; weights stream from L2 (native [768][256] layout, float4).
// Output masked by num_sentences_lens at store.
// ---------------------------------------------------------------------------
__global__ __launch_bounds__(256) void gru_k(
    const float* __restrict__ xpf, const float* __restrict__ xpb,
    const float* __restrict__ whf, const float* __restrict__ whb,
    const float* __restrict__ bhf, const float* __restrict__ bhb,
    const int* __restrict__ lens, float* __restrict__ out)
{
  const int dir = blockIdx.x >> 5;    // 0 fwd, 1 bwd
  const int grp = blockIdx.x & 31;
  const int b0 = grp * 4;
  const float* __restrict__ xp  = dir ? xpb : xpf;
  const float* __restrict__ whh = dir ? whb : whf;
  const float* __restrict__ bhh = dir ? bhb : bhf;
  const int tid = threadIdx.x;        // hidden unit

  __shared__ float hs[4][H_];
#pragma unroll
  for (int b = 0; b < 4; ++b) hs[b][tid] = 0.f;

  const float br = bhh[tid], bz = bhh[H_ + tid], bn = bhh[2 * H_ + tid];
  const float* wr = whh + (size_t)tid * H_;
  const float* wz = whh + (size_t)(H_ + tid) * H_;
  const float* wn = whh + (size_t)(2 * H_ + tid) * H_;
  int len_[4];
#pragma unroll
  for (int b = 0; b < 4; ++b) len_[b] = lens[b0 + b];
  __syncthreads();

  for (int t = 0; t < S_; ++t) {
    float ar[4], az[4], an[4];
#pragma unroll
    for (int b = 0; b < 4; ++b) { ar[b] = br; az[b] = bz; an[b] = bn; }

#pragma unroll 2
    for (int j = 0; j < H_; j += 4) {
      float4 w1 = *(const float4*)(wr + j);
      float4 w2 = *(const float4*)(wz + j);
      float4 w3 = *(const float4*)(wn + j);
#pragma unroll
      for (int b = 0; b < 4; ++b) {
        float4 h4 = *(const float4*)&hs[b][j];
        ar[b] += w1.x * h4.x + w1.y * h4.y + w1.z * h4.z + w1.w * h4.w;
        az[b] += w2.x * h4.x + w2.y * h4.y + w2.z * h4.z + w2.w * h4.w;
        an[b] += w3.x * h4.x + w3.y * h4.y + w3.z * h4.z + w3.w * h4.w;
      }
    }

    const int s_out = dir ? (S_ - 1 - t) : t;
    const float* xprow = xp + ((size_t)t * B_ + b0) * G3_;
    float hn_[4];
#pragma unroll
    for (int b = 0; b < 4; ++b) {
      float xr = xprow[b * G3_ + tid];
      float xz = xprow[b * G3_ + H_ + tid];
      float xn = xprow[b * G3_ + 2 * H_ + tid];
      float r = 1.f / (1.f + __expf(-(xr + ar[b])));
      float z = 1.f / (1.f + __expf(-(xz + az[b])));
      float n = tanhf(xn + r * an[b]);
      hn_[b] = (1.f - z) * n + z * hs[b][tid];
    }
    __syncthreads();   // all reads of hs done
#pragma unroll
    for (int b = 0; b < 4; ++b) {
      hs[b][tid] = hn_[b];
      out[((size_t)(b0 + b) * S_ + s_out) * D2H_ + dir * H_ + tid] =
          (s_out < len_[b]) ? hn_[b] : 0.f;
    }
    __syncthreads();   // hs ready for next step
  }
}

// ---------------------------------------------------------------------------
// K3: proj[b,s,c] = out[b,s,:] . proj_w[c,:] + proj_b[c]   (M=16384,N=256,K=512)
// ---------------------------------------------------------------------------
__global__ __launch_bounds__(256) void proj_gemm(
    const float* __restrict__ a, const float* __restrict__ w,
    const float* __restrict__ bias, float* __restrict__ proj)
{
  const int bm = blockIdx.x;          // 0..255
  const int n0 = blockIdx.y * 64;     // 0..192

  __shared__ float As[16][68];
  __shared__ float Bs[16][68];

  const int tid = threadIdx.x;
  const int row = tid >> 2;
  const int kq  = (tid & 3) << 2;
  const int tx  = tid & 15, ty = tid >> 4;

  const float* arow = a + (size_t)(bm * 64 + row) * D2H_ + kq;
  const float* brow = w + (size_t)(n0 + row) * D2H_ + kq;

  float acc[4][4] = {};

  for (int k0 = 0; k0 < D2H_; k0 += 16) {
    float4 av = *(const float4*)(arow + k0);
    float4 bv = *(const float4*)(brow + k0);
    As[kq + 0][row] = av.x; As[kq + 1][row] = av.y;
    As[kq + 2][row] = av.z; As[kq + 3][row] = av.w;
    Bs[kq + 0][row] = bv.x; Bs[kq + 1][row] = bv.y;
    Bs[kq + 2][row] = bv.z; Bs[kq + 3][row] = bv.w;
    __syncthreads();
#pragma unroll
    for (int k = 0; k < 16; ++k) {
      float4 av2 = *(const float4*)&As[k][ty * 4];
      float4 bv2 = *(const float4*)&Bs[k][tx * 4];
      acc[0][0] += av2.x * bv2.x; acc[0][1] += av2.x * bv2.y; acc[0][2] += av2.x * bv2.z; acc[0][3] += av2.x * bv2.w;
      acc[1][0] += av2.y * bv2.x; acc[1][1] += av2.y * bv2.y; acc[1][2] += av2.y * bv2.z; acc[1][3] += av2.y * bv2.w;
      acc[2][0] += av2.z * bv2.x; acc[2][1] += av2.z * bv2.y; acc[2][2] += av2.z * bv2.z; acc[2][3] += av2.z * bv2.w;
      acc[3][0] += av2.w * bv2.x; acc[3][1] += av2.w * bv2.y; acc[3][2] += av2.w * bv2.z; acc[3][3] += av2.w * bv2.w;
    }
    __syncthreads();
  }

  float4 bv4 = *(const float4*)(bias + n0 + tx * 4);
#pragma unroll
  for (int i = 0; i < 4; ++i) {
    int m = bm * 64 + ty * 4 + i;
    float4 o;
    o.x = acc[i][0] + bv4.x; o.y = acc[i][1] + bv4.y;
    o.z = acc[i][2] + bv4.z; o.w = acc[i][3] + bv4.w;
    *(float4*)(proj + (size_t)m * C_ + n0 + tx * 4) = o;
  }
}

// ---------------------------------------------------------------------------
// K4: BatchNorm stats per s over (b, c): mu[s], rstd[s]
// ---------------------------------------------------------------------------
__global__ __launch_bounds__(256) void bn_stats(
    const float* __restrict__ proj, float* __restrict__ mu, float* __restrict__ rstd)
{
  const int s = blockIdx.x, tid = threadIdx.x;  // tid = c
  float sum = 0.f, sq = 0.f;
  for (int b = 0; b < B_; ++b) {
    float v = proj[((size_t)b * S_ + s) * C_ + tid];
    sum += v; sq += v * v;
  }
#pragma unroll
  for (int o = 32; o; o >>= 1) { sum += __shfl_down(sum, o); sq += __shfl_down(sq, o); }
  __shared__ float r1[4], r2[4];
  const int lane = tid & 63, wid = tid >> 6;
  if (!lane) { r1[wid] = sum; r2[wid] = sq; }
  __syncthreads();
  if (!tid) {
    float s1 = r1[0] + r1[1] + r1[2] + r1[3];
    float s2 = r2[0] + r2[1] + r2[2] + r2[3];
    float m = s1 / (float)(B_ * C_);
    float var = s2 / (float)(B_ * C_) - m * m;
    mu[s] = m;
    rstd[s] = rsqrtf(var + 1e-5f);
  }
}

// ---------------------------------------------------------------------------
// K5: scores[b,s] = sum_c relu(bn(proj)) * ctx[c]. One wave per (b,s).
// ---------------------------------------------------------------------------
__global__ __launch_bounds__(256) void score_k(
    const float* __restrict__ proj, const float* __restrict__ mu,
    const float* __restrict__ rstd, const float* __restrict__ gamma,
    const float* __restrict__ beta, const float* __restrict__ ctx,
    float* __restrict__ scores)
{
  const int wid = threadIdx.x >> 6, lane = threadIdx.x & 63;
  const int m = blockIdx.x * 4 + wid;     // b*128+s
  const int s = m & 127;
  float4 v  = *(const float4*)(proj + (size_t)m * C_ + lane * 4);
  float4 cv = *(const float4*)(ctx + lane * 4);
  const float ms = mu[s], rs = rstd[s], g = gamma[s], be = beta[s];
  float acc = fmaxf((v.x - ms) * rs * g + be, 0.f) * cv.x
            + fmaxf((v.y - ms) * rs * g + be, 0.f) * cv.y
            + fmaxf((v.z - ms) * rs * g + be, 0.f) * cv.z
            + fmaxf((v.w - ms) * rs * g + be, 0.f) * cv.w;
#pragma unroll
  for (int o = 32; o; o >>= 1) acc += __shfl_down(acc, o);
  if (!lane) scores[m] = acc;
}

// ---------------------------------------------------------------------------
// K6: softmax over s per b
// ---------------------------------------------------------------------------
__global__ __launch_bounds__(128) void softmax_k(
    const float* __restrict__ scores, float* __restrict__ attn)
{
  const int b = blockIdx.x, tid = threadIdx.x;
  float v = scores[b * S_ + tid];
  float mx = v;
#pragma unroll
  for (int o = 32; o; o >>= 1) mx = fmaxf(mx, __shfl_down(mx, o));
  __shared__ float t0[2], t1[2];
  const int lane = tid & 63, wid = tid >> 6;
  if (!lane) t0[wid] = mx;
  __syncthreads();
  mx = fmaxf(t0[0], t0[1]);
  float e = __expf(v - mx);
  float ssum = e;
#pragma unroll
  for (int o = 32; o; o >>= 1) ssum += __shfl_down(ssum, o);
  if (!lane) t1[wid] = ssum;
  __syncthreads();
  attn[b * S_ + tid] = e / (t1[0] + t1[1]);
}

// ---------------------------------------------------------------------------
// K7: y[b,d] = sum_s attn[b,s] * out[b,s,d]
// ---------------------------------------------------------------------------
__global__ __launch_bounds__(512) void final_k(
    const float* __restrict__ attn, const float* __restrict__ out,
    float* __restrict__ y)
{
  const int b = blockIdx.x, d = threadIdx.x;
  __shared__ float a[S_];
  if (threadIdx.x < S_) a[threadIdx.x] = attn[b * S_ + threadIdx.x];
  __syncthreads();
  float acc = 0.f;
  for (int s = 0; s < S_; ++s)
    acc += a[s] * out[((size_t)b * S_ + s) * D2H_ + d];
  y[(size_t)b * D2H_ + d] = acc;
}

// ---------------------------------------------------------------------------
extern "C" void kernel_launch(void* const* d_in, const int* in_sizes, int n_in,
                              void* d_out, int out_size, void* d_ws, size_t ws_size,
                              hipStream_t stream)
{
  const float* x      = (const float*)d_in[0];
  // d_in[1] sent_hidden_stat: unused
  const int*   lens   = (const int*)d_in[2];
  const float* w_ih_f = (const float*)d_in[3];
  const float* w_hh_f = (const float*)d_in[4];
  const float* b_ih_f = (const float*)d_in[5];
  const float* b_hh_f = (const float*)d_in[6];
  const float* w_ih_b = (const float*)d_in[7];
  const float* w_hh_b = (const float*)d_in[8];
  const float* b_ih_b = (const float*)d_in[9];
  const float* b_hh_b = (const float*)d_in[10];
  const float* proj_w = (const float*)d_in[11];
  const float* proj_b = (const float*)d_in[12];
  const float* gamma  = (const float*)d_in[13];
  const float* beta   = (const float*)d_in[14];
  const float* ctx    = (const float*)d_in[15];

  float* ws = (float*)d_ws;
  // high-water layout: xpf | xpb | out   (128 MiB)
  float* xpf  = ws;                       // 12,582,912 f
  float* xpb  = ws + 12582912;            // 12,582,912 f
  float* outm = ws + 25165824;            //  8,388,608 f
  // after gru_k, xp regions are dead -> alias epilogue buffers there
  float* proj   = ws;                     //  4,194,304 f
  float* mu     = ws + 4194304;           //  128
  float* rstd   = ws + 4194432;           //  128
  float* scores = ws + 4194560;           //  16,384
  float* attn   = ws + 4210944;           //  16,384

  xp_gemm<<<dim3(256, 24), 256, 0, stream>>>(x, w_ih_f, w_ih_b, b_ih_f, b_ih_b, xpf, xpb);
  gru_k<<<64, 256, 0, stream>>>(xpf, xpb, w_hh_f, w_hh_b, b_hh_f, b_hh_b, lens, outm);
  proj_gemm<<<dim3(256, 4), 256, 0, stream>>>(outm, proj_w, proj_b, proj);
  bn_stats<<<128, 256, 0, stream>>>(proj, mu, rstd);
  score_k<<<4096, 256, 0, stream>>>(proj, mu, rstd, gamma, beta, ctx, scores);
  softmax_k<<<128, 128, 0, stream>>>(scores, attn);
  final_k<<<128, 512, 0, stream>>>(attn, outm, (float*)d_out);
}

// Round 2
// 1011.511 us; speedup vs baseline: 3.3502x; 3.3502x over previous
//
#include <hip/hip_runtime.h>
#include <hip/hip_bf16.h>

#define B_   128
#define S_   128
#define IN_  512
#define H_   256
#define G3_  768   // 3*H
#define C_   256
#define D2H_ 512   // 2*H

typedef short bf16x8 __attribute__((ext_vector_type(8)));
typedef float f32x4  __attribute__((ext_vector_type(4)));

static __device__ __forceinline__ short f2bf(float f) {
  unsigned u = __float_as_uint(f);
  return (short)((u + 0x7fffu + ((u >> 16) & 1u)) >> 16);
}

// ---------------------------------------------------------------------------
// K1: xp = x @ [w_ih_f; w_ih_b]^T + b_ih  (both directions in one GEMM)
// ---------------------------------------------------------------------------
__global__ __launch_bounds__(256) void xp_gemm(
    const float* __restrict__ x,
    const float* __restrict__ wf, const float* __restrict__ wb,
    const float* __restrict__ bf, const float* __restrict__ bb,
    float* __restrict__ xpf, float* __restrict__ xpb)
{
  const int bm = blockIdx.x;          // 0..255
  const int n0 = blockIdx.y * 64;     // 0..1472
  const bool fwd = (n0 < G3_);
  const float* __restrict__ w    = fwd ? wf : wb;
  const float* __restrict__ bias = fwd ? bf : bb;
  const int nc0 = fwd ? n0 : (n0 - G3_);

  __shared__ float As[16][68];
  __shared__ float Bs[16][68];

  const int tid = threadIdx.x;
  const int row = tid >> 2;
  const int kq  = (tid & 3) << 2;
  const int tx  = tid & 15, ty = tid >> 4;

  const float* arow = x + (size_t)(bm * 64 + row) * IN_ + kq;
  const float* brow = w + (size_t)(nc0 + row) * IN_ + kq;

  float acc[4][4] = {};

  for (int k0 = 0; k0 < IN_; k0 += 16) {
    float4 av = *(const float4*)(arow + k0);
    float4 bv = *(const float4*)(brow + k0);
    As[kq + 0][row] = av.x; As[kq + 1][row] = av.y;
    As[kq + 2][row] = av.z; As[kq + 3][row] = av.w;
    Bs[kq + 0][row] = bv.x; Bs[kq + 1][row] = bv.y;
    Bs[kq + 2][row] = bv.z; Bs[kq + 3][row] = bv.w;
    __syncthreads();
#pragma unroll
    for (int k = 0; k < 16; ++k) {
      float4 a = *(const float4*)&As[k][ty * 4];
      float4 b = *(const float4*)&Bs[k][tx * 4];
      acc[0][0] += a.x * b.x; acc[0][1] += a.x * b.y; acc[0][2] += a.x * b.z; acc[0][3] += a.x * b.w;
      acc[1][0] += a.y * b.x; acc[1][1] += a.y * b.y; acc[1][2] += a.y * b.z; acc[1][3] += a.y * b.w;
      acc[2][0] += a.z * b.x; acc[2][1] += a.z * b.y; acc[2][2] += a.z * b.z; acc[2][3] += a.z * b.w;
      acc[3][0] += a.w * b.x; acc[3][1] += a.w * b.y; acc[3][2] += a.w * b.z; acc[3][3] += a.w * b.w;
    }
    __syncthreads();
  }

  float4 bv4 = *(const float4*)(bias + nc0 + tx * 4);
#pragma unroll
  for (int i = 0; i < 4; ++i) {
    int m = bm * 64 + ty * 4 + i;
    int b = m >> 7, s = m & 127;
    float4 o;
    o.x = acc[i][0] + bv4.x; o.y = acc[i][1] + bv4.y;
    o.z = acc[i][2] + bv4.z; o.w = acc[i][3] + bv4.w;
    if (fwd)
      *(float4*)(xpf + ((size_t)s * B_ + b) * G3_ + nc0 + tx * 4) = o;
    else
      *(float4*)(xpb + ((size_t)(S_ - 1 - s) * B_ + b) * G3_ + nc0 + tx * 4) = o;
  }
}

// ---------------------------------------------------------------------------
// K2: GRU recurrence, MFMA, weights register-resident.
// 16 blocks = 2 dirs x 8 groups of 16 batches. 512 threads = 8 waves.
// Wave w owns units [32w, 32w+32) as two 16-unit triplets (r,z,n tiles).
// B-frags (W_hh, bf16) live in VGPRs for all 128 steps. h: fp32 in regs
// (per-lane 4 batches x 2 units), bf16 copy in LDS for the MFMA A operand.
// acc init = xp(t) + b_hh (MFMA C-in); single barrier per step.
// ---------------------------------------------------------------------------
__global__ __launch_bounds__(512, 2) void gru_mfma(
    const float* __restrict__ xpf, const float* __restrict__ xpb,
    const float* __restrict__ whf, const float* __restrict__ whb,
    const float* __restrict__ bhf, const float* __restrict__ bhb,
    const int* __restrict__ lens, float* __restrict__ out)
{
  const int dir = blockIdx.x >> 3;
  const int b0  = (blockIdx.x & 7) * 16;
  const float* __restrict__ xp  = dir ? xpb : xpf;
  const float* __restrict__ whh = dir ? whb : whf;
  const float* __restrict__ bhh = dir ? bhb : bhf;

  const int tid  = threadIdx.x;
  const int wave = tid >> 6;
  const int lane = tid & 63;
  const int col  = lane & 15;   // A-row (batch-ish for C rows) / B-col (unit)
  const int lg   = lane >> 4;   // k-group

  // units owned by this lane: tt=0 -> u0, tt=1 -> u0+16
  const int gb0 = wave * 32 + col;
  const int gb1 = gb0 + 16;

  __shared__ unsigned short hlds[2][32][16][8];   // [buf][kblk][batch][j] 16KB

  // ---- prologue: zero h buffer 0 ----
  {
    int4* z = (int4*)&hlds[0][0][0][0];
    z[tid] = int4{0, 0, 0, 0};   // 512 * 16B = 8KB
  }

  // ---- load W_hh fragments (bf16, packed) ----
  bf16x8 wfg[2][3][8];
#pragma unroll
  for (int tt = 0; tt < 2; ++tt) {
    const int gbase = tt ? gb1 : gb0;
#pragma unroll
    for (int g = 0; g < 3; ++g) {
      const float* wrow = whh + (size_t)(g * H_ + gbase) * H_;
#pragma unroll
      for (int kk = 0; kk < 8; ++kk) {
        const float* p = wrow + kk * 32 + lg * 8;
        float4 w0 = *(const float4*)p;
        float4 w1 = *(const float4*)(p + 4);
        bf16x8 f;
        f[0] = f2bf(w0.x); f[1] = f2bf(w0.y); f[2] = f2bf(w0.z); f[3] = f2bf(w0.w);
        f[4] = f2bf(w1.x); f[5] = f2bf(w1.y); f[6] = f2bf(w1.z); f[7] = f2bf(w1.w);
        wfg[tt][g][kk] = f;
      }
    }
  }

  // per-lane b_hh
  float bhr[2], bhz[2], bhn[2];
#pragma unroll
  for (int tt = 0; tt < 2; ++tt) {
    const int gbase = tt ? gb1 : gb0;
    bhr[tt] = bhh[gbase];
    bhz[tt] = bhh[H_ + gbase];
    bhn[tt] = bhh[2 * H_ + gbase];
  }

  int len_[4];
#pragma unroll
  for (int i = 0; i < 4; ++i) len_[i] = lens[b0 + lg * 4 + i];

  // fp32 hidden state carried in registers (never round-trips through bf16)
  float hreg[2][4] = {};

  // acc / xn; xp(t=0) preload
  f32x4 accv[2][3];
  float xnv[2][4];
  {
    const float* xprow = xp + (size_t)b0 * G3_;   // t = 0
#pragma unroll
    for (int tt = 0; tt < 2; ++tt) {
      const int gbase = tt ? gb1 : gb0;
#pragma unroll
      for (int i = 0; i < 4; ++i) {
        const size_t bo = (size_t)(lg * 4 + i) * G3_;
        accv[tt][0][i] = xprow[bo + gbase];
        accv[tt][1][i] = xprow[bo + H_ + gbase];
        xnv[tt][i]     = xprow[bo + 2 * H_ + gbase];
      }
    }
  }

  __syncthreads();

  int buf = 0;
  for (int t = 0; t < S_; ++t) {
    // finish acc init: + b_hh  (n-acc starts at b_hh_n only)
#pragma unroll
    for (int tt = 0; tt < 2; ++tt) {
#pragma unroll
      for (int i = 0; i < 4; ++i) {
        accv[tt][0][i] += bhr[tt];
        accv[tt][1][i] += bhz[tt];
      }
      accv[tt][2][0] = bhn[tt]; accv[tt][2][1] = bhn[tt];
      accv[tt][2][2] = bhn[tt]; accv[tt][2][3] = bhn[tt];
    }

    // MFMA phase: gates += h @ W^T
#pragma unroll
    for (int kk = 0; kk < 8; ++kk) {
      bf16x8 a = *(const bf16x8*)&hlds[buf][kk * 4 + lg][col][0];
#pragma unroll
      for (int tt = 0; tt < 2; ++tt) {
        accv[tt][0] = __builtin_amdgcn_mfma_f32_16x16x32_bf16(a, wfg[tt][0][kk], accv[tt][0], 0, 0, 0);
        accv[tt][1] = __builtin_amdgcn_mfma_f32_16x16x32_bf16(a, wfg[tt][1][kk], accv[tt][1], 0, 0, 0);
        accv[tt][2] = __builtin_amdgcn_mfma_f32_16x16x32_bf16(a, wfg[tt][2][kk], accv[tt][2], 0, 0, 0);
      }
    }

    const int s_out = dir ? (S_ - 1 - t) : t;

    // nonlinearity + state update + stores
#pragma unroll
    for (int tt = 0; tt < 2; ++tt) {
      const int u  = tt ? gb1 : gb0;
      const int kb = u >> 3, jj = u & 7;
#pragma unroll
      for (int i = 0; i < 4; ++i) {
        const int bi = lg * 4 + i;
        float r = 1.f / (1.f + __expf(-accv[tt][0][i]));
        float z = 1.f / (1.f + __expf(-accv[tt][1][i]));
        float nx = xnv[tt][i] + r * accv[tt][2][i];
        float n = 1.f - 2.f / (__expf(2.f * nx) + 1.f);
        float hn = n + z * (hreg[tt][i] - n);
        hreg[tt][i] = hn;
        out[((size_t)(b0 + bi) * S_ + s_out) * D2H_ + dir * H_ + u] =
            (s_out < len_[i]) ? hn : 0.f;
        hlds[buf ^ 1][kb][bi][jj] = (unsigned short)f2bf(hn);
      }
    }

    // prefetch next step's xp into the (now free) accumulators
    if (t + 1 < S_) {
      const float* xprow = xp + (size_t)(t + 1) * B_ * G3_ + (size_t)b0 * G3_;
#pragma unroll
      for (int tt = 0; tt < 2; ++tt) {
        const int gbase = tt ? gb1 : gb0;
#pragma unroll
        for (int i = 0; i < 4; ++i) {
          const size_t bo = (size_t)(lg * 4 + i) * G3_;
          accv[tt][0][i] = xprow[bo + gbase];
          accv[tt][1][i] = xprow[bo + H_ + gbase];
          xnv[tt][i]     = xprow[bo + 2 * H_ + gbase];
        }
      }
    }

    __syncthreads();
    buf ^= 1;
  }
}

// ---------------------------------------------------------------------------
// K3: proj[b,s,c] = out[b,s,:] . proj_w[c,:] + proj_b[c]
// ---------------------------------------------------------------------------
__global__ __launch_bounds__(256) void proj_gemm(
    const float* __restrict__ a, const float* __restrict__ w,
    const float* __restrict__ bias, float* __restrict__ proj)
{
  const int bm = blockIdx.x;
  const int n0 = blockIdx.y * 64;

  __shared__ float As[16][68];
  __shared__ float Bs[16][68];

  const int tid = threadIdx.x;
  const int row = tid >> 2;
  const int kq  = (tid & 3) << 2;
  const int tx  = tid & 15, ty = tid >> 4;

  const float* arow = a + (size_t)(bm * 64 + row) * D2H_ + kq;
  const float* brow = w + (size_t)(n0 + row) * D2H_ + kq;

  float acc[4][4] = {};

  for (int k0 = 0; k0 < D2H_; k0 += 16) {
    float4 av = *(const float4*)(arow + k0);
    float4 bv = *(const float4*)(brow + k0);
    As[kq + 0][row] = av.x; As[kq + 1][row] = av.y;
    As[kq + 2][row] = av.z; As[kq + 3][row] = av.w;
    Bs[kq + 0][row] = bv.x; Bs[kq + 1][row] = bv.y;
    Bs[kq + 2][row] = bv.z; Bs[kq + 3][row] = bv.w;
    __syncthreads();
#pragma unroll
    for (int k = 0; k < 16; ++k) {
      float4 av2 = *(const float4*)&As[k][ty * 4];
      float4 bv2 = *(const float4*)&Bs[k][tx * 4];
      acc[0][0] += av2.x * bv2.x; acc[0][1] += av2.x * bv2.y; acc[0][2] += av2.x * bv2.z; acc[0][3] += av2.x * bv2.w;
      acc[1][0] += av2.y * bv2.x; acc[1][1] += av2.y * bv2.y; acc[1][2] += av2.y * bv2.z; acc[1][3] += av2.y * bv2.w;
      acc[2][0] += av2.z * bv2.x; acc[2][1] += av2.z * bv2.y; acc[2][2] += av2.z * bv2.z; acc[2][3] += av2.z * bv2.w;
      acc[3][0] += av2.w * bv2.x; acc[3][1] += av2.w * bv2.y; acc[3][2] += av2.w * bv2.z; acc[3][3] += av2.w * bv2.w;
    }
    __syncthreads();
  }

  float4 bv4 = *(const float4*)(bias + n0 + tx * 4);
#pragma unroll
  for (int i = 0; i < 4; ++i) {
    int m = bm * 64 + ty * 4 + i;
    float4 o;
    o.x = acc[i][0] + bv4.x; o.y = acc[i][1] + bv4.y;
    o.z = acc[i][2] + bv4.z; o.w = acc[i][3] + bv4.w;
    *(float4*)(proj + (size_t)m * C_ + n0 + tx * 4) = o;
  }
}

// ---------------------------------------------------------------------------
__global__ __launch_bounds__(256) void bn_stats(
    const float* __restrict__ proj, float* __restrict__ mu, float* __restrict__ rstd)
{
  const int s = blockIdx.x, tid = threadIdx.x;
  float sum = 0.f, sq = 0.f;
  for (int b = 0; b < B_; ++b) {
    float v = proj[((size_t)b * S_ + s) * C_ + tid];
    sum += v; sq += v * v;
  }
#pragma unroll
  for (int o = 32; o; o >>= 1) { sum += __shfl_down(sum, o); sq += __shfl_down(sq, o); }
  __shared__ float r1[4], r2[4];
  const int lane = tid & 63, wid = tid >> 6;
  if (!lane) { r1[wid] = sum; r2[wid] = sq; }
  __syncthreads();
  if (!tid) {
    float s1 = r1[0] + r1[1] + r1[2] + r1[3];
    float s2 = r2[0] + r2[1] + r2[2] + r2[3];
    float m = s1 / (float)(B_ * C_);
    float var = s2 / (float)(B_ * C_) - m * m;
    mu[s] = m;
    rstd[s] = rsqrtf(var + 1e-5f);
  }
}

__global__ __launch_bounds__(256) void score_k(
    const float* __restrict__ proj, const float* __restrict__ mu,
    const float* __restrict__ rstd, const float* __restrict__ gamma,
    const float* __restrict__ beta, const float* __restrict__ ctx,
    float* __restrict__ scores)
{
  const int wid = threadIdx.x >> 6, lane = threadIdx.x & 63;
  const int m = blockIdx.x * 4 + wid;
  const int s = m & 127;
  float4 v  = *(const float4*)(proj + (size_t)m * C_ + lane * 4);
  float4 cv = *(const float4*)(ctx + lane * 4);
  const float ms = mu[s], rs = rstd[s], g = gamma[s], be = beta[s];
  float acc = fmaxf((v.x - ms) * rs * g + be, 0.f) * cv.x
            + fmaxf((v.y - ms) * rs * g + be, 0.f) * cv.y
            + fmaxf((v.z - ms) * rs * g + be, 0.f) * cv.z
            + fmaxf((v.w - ms) * rs * g + be, 0.f) * cv.w;
#pragma unroll
  for (int o = 32; o; o >>= 1) acc += __shfl_down(acc, o);
  if (!lane) scores[m] = acc;
}

__global__ __launch_bounds__(128) void softmax_k(
    const float* __restrict__ scores, float* __restrict__ attn)
{
  const int b = blockIdx.x, tid = threadIdx.x;
  float v = scores[b * S_ + tid];
  float mx = v;
#pragma unroll
  for (int o = 32; o; o >>= 1) mx = fmaxf(mx, __shfl_down(mx, o));
  __shared__ float t0[2], t1[2];
  const int lane = tid & 63, wid = tid >> 6;
  if (!lane) t0[wid] = mx;
  __syncthreads();
  mx = fmaxf(t0[0], t0[1]);
  float e = __expf(v - mx);
  float ssum = e;
#pragma unroll
  for (int o = 32; o; o >>= 1) ssum += __shfl_down(ssum, o);
  if (!lane) t1[wid] = ssum;
  __syncthreads();
  attn[b * S_ + tid] = e / (t1[0] + t1[1]);
}

__global__ __launch_bounds__(512) void final_k(
    const float* __restrict__ attn, const float* __restrict__ out,
    float* __restrict__ y)
{
  const int b = blockIdx.x, d = threadIdx.x;
  __shared__ float a[S_];
  if (threadIdx.x < S_) a[threadIdx.x] = attn[b * S_ + threadIdx.x];
  __syncthreads();
  float acc = 0.f;
  for (int s = 0; s < S_; ++s)
    acc += a[s] * out[((size_t)b * S_ + s) * D2H_ + d];
  y[(size_t)b * D2H_ + d] = acc;
}

// ---------------------------------------------------------------------------
extern "C" void kernel_launch(void* const* d_in, const int* in_sizes, int n_in,
                              void* d_out, int out_size, void* d_ws, size_t ws_size,
                              hipStream_t stream)
{
  const float* x      = (const float*)d_in[0];
  const int*   lens   = (const int*)d_in[2];
  const float* w_ih_f = (const float*)d_in[3];
  const float* w_hh_f = (const float*)d_in[4];
  const float* b_ih_f = (const float*)d_in[5];
  const float* b_hh_f = (const float*)d_in[6];
  const float* w_ih_b = (const float*)d_in[7];
  const float* w_hh_b = (const float*)d_in[8];
  const float* b_ih_b = (const float*)d_in[9];
  const float* b_hh_b = (const float*)d_in[10];
  const float* proj_w = (const float*)d_in[11];
  const float* proj_b = (const float*)d_in[12];
  const float* gamma  = (const float*)d_in[13];
  const float* beta   = (const float*)d_in[14];
  const float* ctx    = (const float*)d_in[15];

  float* ws = (float*)d_ws;
  float* xpf  = ws;                       // 12,582,912 f
  float* xpb  = ws + 12582912;            // 12,582,912 f
  float* outm = ws + 25165824;            //  8,388,608 f
  float* proj   = ws;                     // aliases dead xp region
  float* mu     = ws + 4194304;
  float* rstd   = ws + 4194432;
  float* scores = ws + 4194560;
  float* attn   = ws + 4210944;

  xp_gemm<<<dim3(256, 24), 256, 0, stream>>>(x, w_ih_f, w_ih_b, b_ih_f, b_ih_b, xpf, xpb);
  gru_mfma<<<16, 512, 0, stream>>>(xpf, xpb, w_hh_f, w_hh_b, b_hh_f, b_hh_b, lens, outm);
  proj_gemm<<<dim3(256, 4), 256, 0, stream>>>(outm, proj_w, proj_b, proj);
  bn_stats<<<128, 256, 0, stream>>>(proj, mu, rstd);
  score_k<<<4096, 256, 0, stream>>>(proj, mu, rstd, gamma, beta, ctx, scores);
  softmax_k<<<128, 128, 0, stream>>>(scores, attn);
  final_k<<<128, 512, 0, stream>>>(attn, outm, (float*)d_out);
}

// Round 3
// 645.658 us; speedup vs baseline: 5.2485x; 1.5666x over previous
//
#include <hip/hip_runtime.h>
#include <hip/hip_bf16.h>

#define B_   128
#define S_   128
#define IN_  512
#define H_   256
#define G3_  768   // 3*H
#define C_   256
#define D2H_ 512   // 2*H

typedef short bf16x8 __attribute__((ext_vector_type(8)));
typedef float f32x4  __attribute__((ext_vector_type(4)));

static __device__ __forceinline__ short f2bf(float f) {
  unsigned u = __float_as_uint(f);
  return (short)((u + 0x7fffu + ((u >> 16) & 1u)) >> 16);
}

// async global->LDS, 16B per lane. LDS dest must be wave-uniform (HW adds lane*16).
static __device__ __forceinline__ void async16(const float* g, const void* l) {
  __builtin_amdgcn_global_load_lds(
      (const __attribute__((address_space(1))) void*)g,
      (__attribute__((address_space(3))) void*)l, 16, 0, 0);
}

// ---------------------------------------------------------------------------
// K1: xp = x @ [w_ih]^T + (b_ih [+ b_hh for r,z gates])   bf16 MFMA
// A: x rows m=b*128+s, but blocked s-fixed: block bm=s covers all b (M=128).
// Output layout: xp[dir][t][g][b]  (t = s fwd, 127-s bwd; g 0..767; b 0..127)
// Grid (128, 12): y<6 -> fwd cols bn*128.., y>=6 -> bwd.
// ---------------------------------------------------------------------------
__global__ __launch_bounds__(256) void xp_gemm_bf(
    const float* __restrict__ x,
    const float* __restrict__ wf, const float* __restrict__ wb,
    const float* __restrict__ bif, const float* __restrict__ bhf,
    const float* __restrict__ bib, const float* __restrict__ bhb,
    float* __restrict__ xpf, float* __restrict__ xpb)
{
  const int sb = blockIdx.x;                 // s = 0..127
  const int bn = blockIdx.y;                 // 0..11
  const bool fwd = (bn < 6);
  const float* __restrict__ wsrc = fwd ? wf : wb;
  const float* __restrict__ bi   = fwd ? bif : bib;
  const float* __restrict__ bh   = fwd ? bhf : bhb;
  const int nloc0 = (fwd ? bn : bn - 6) * 128;   // col base within dir (0..640)

  __shared__ __align__(16) unsigned short As[128][56];  // stride 112B: 16B-mult, 2-way banks
  __shared__ __align__(16) unsigned short Bs[128][56];

  const int tid  = threadIdx.x;
  const int wave = tid >> 6, lane = tid & 63;
  const int col  = lane & 15, lg = lane >> 4;
  const int wm   = wave >> 1, wn = wave & 1;
  const int rr   = tid >> 1;                 // staging row 0..127
  const int hf   = (tid & 1) * 16;           // staging elem offset 0/16

  const float* ax = x    + ((size_t)(rr * 128 + sb) * IN_ + hf);
  const float* bx = wsrc + ((size_t)(nloc0 + rr) * IN_ + hf);

  f32x4 acc[4][4];
#pragma unroll
  for (int i = 0; i < 4; ++i)
#pragma unroll
    for (int j = 0; j < 4; ++j) acc[i][j] = f32x4{0.f, 0.f, 0.f, 0.f};

  for (int k0 = 0; k0 < IN_; k0 += 32) {
    float4 a0 = *(const float4*)(ax + k0);
    float4 a1 = *(const float4*)(ax + k0 + 4);
    float4 a2 = *(const float4*)(ax + k0 + 8);
    float4 a3 = *(const float4*)(ax + k0 + 12);
    float4 c0 = *(const float4*)(bx + k0);
    float4 c1 = *(const float4*)(bx + k0 + 4);
    float4 c2 = *(const float4*)(bx + k0 + 8);
    float4 c3 = *(const float4*)(bx + k0 + 12);
    __syncthreads();   // previous iter's frag reads done
    {
      bf16x8 p0, p1;
      p0[0]=f2bf(a0.x); p0[1]=f2bf(a0.y); p0[2]=f2bf(a0.z); p0[3]=f2bf(a0.w);
      p0[4]=f2bf(a1.x); p0[5]=f2bf(a1.y); p0[6]=f2bf(a1.z); p0[7]=f2bf(a1.w);
      p1[0]=f2bf(a2.x); p1[1]=f2bf(a2.y); p1[2]=f2bf(a2.z); p1[3]=f2bf(a2.w);
      p1[4]=f2bf(a3.x); p1[5]=f2bf(a3.y); p1[6]=f2bf(a3.z); p1[7]=f2bf(a3.w);
      *(bf16x8*)&As[rr][hf]     = p0;
      *(bf16x8*)&As[rr][hf + 8] = p1;
      p0[0]=f2bf(c0.x); p0[1]=f2bf(c0.y); p0[2]=f2bf(c0.z); p0[3]=f2bf(c0.w);
      p0[4]=f2bf(c1.x); p0[5]=f2bf(c1.y); p0[6]=f2bf(c1.z); p0[7]=f2bf(c1.w);
      p1[0]=f2bf(c2.x); p1[1]=f2bf(c2.y); p1[2]=f2bf(c2.z); p1[3]=f2bf(c2.w);
      p1[4]=f2bf(c3.x); p1[5]=f2bf(c3.y); p1[6]=f2bf(c3.z); p1[7]=f2bf(c3.w);
      *(bf16x8*)&Bs[rr][hf]     = p0;
      *(bf16x8*)&Bs[rr][hf + 8] = p1;
    }
    __syncthreads();
    bf16x8 af[4], bf_[4];
#pragma unroll
    for (int mi = 0; mi < 4; ++mi)
      af[mi] = *(const bf16x8*)&As[wm * 64 + mi * 16 + col][lg * 8];
#pragma unroll
    for (int ni = 0; ni < 4; ++ni)
      bf_[ni] = *(const bf16x8*)&Bs[wn * 64 + ni * 16 + col][lg * 8];
#pragma unroll
    for (int mi = 0; mi < 4; ++mi)
#pragma unroll
      for (int ni = 0; ni < 4; ++ni)
        acc[mi][ni] = __builtin_amdgcn_mfma_f32_16x16x32_bf16(af[mi], bf_[ni], acc[mi][ni], 0, 0, 0);
  }

  // epilogue: bias fold (+b_hh for gates r,z) and [t][g][b] scatter (float4 over b)
  const int t = fwd ? sb : (S_ - 1 - sb);
  float* __restrict__ dstbase = fwd ? xpf : xpb;
#pragma unroll
  for (int ni = 0; ni < 4; ++ni) {
    const int g = nloc0 + wn * 64 + ni * 16 + col;       // 0..767 within dir
    const float bias = bi[g] + (g < 2 * H_ ? bh[g] : 0.f);
#pragma unroll
    for (int mi = 0; mi < 4; ++mi) {
      const int bl = wm * 64 + mi * 16 + lg * 4;         // batch base
      float4 o;
      o.x = acc[mi][ni][0] + bias;
      o.y = acc[mi][ni][1] + bias;
      o.z = acc[mi][ni][2] + bias;
      o.w = acc[mi][ni][3] + bias;
      *(float4*)(dstbase + ((size_t)t * G3_ + g) * B_ + bl) = o;
    }
  }
}

// ---------------------------------------------------------------------------
// K2: GRU recurrence, MFMA, W_hh register-resident, xp LDS-staged (async).
// 16 blocks = 2 dirs x 8 groups of 16 batches; 512 threads = 8 waves.
// xp layout [t][g][b]: block slice staged 48KB/step via global_load_lds,
// double-buffered, issued right after the step barrier (1 step of flight;
// __syncthreads' vmcnt(0) drain is the completion wait).
// b_hh(r,z) pre-folded into xp; b_hh_n seeds the n accumulator.
// ---------------------------------------------------------------------------
__global__ __launch_bounds__(512, 2) void gru_mfma(
    const float* __restrict__ xpf, const float* __restrict__ xpb,
    const float* __restrict__ whf, const float* __restrict__ whb,
    const float* __restrict__ bhf, const float* __restrict__ bhb,
    const int* __restrict__ lens, float* __restrict__ out)
{
  const int dir = blockIdx.x >> 3;
  const int b0  = (blockIdx.x & 7) * 16;
  const float* __restrict__ xp  = dir ? xpb : xpf;
  const float* __restrict__ whh = dir ? whb : whf;
  const float* __restrict__ bhh = dir ? bhb : bhf;

  const int tid  = threadIdx.x;
  const int wave = tid >> 6;
  const int lane = tid & 63;
  const int col  = lane & 15;
  const int lg   = lane >> 4;
  const int gb0  = wave * 32 + col;

  __shared__ __align__(16) unsigned short hlds[2][32][16][8];  // 16KB [buf][k/8][b][k%8]
  __shared__ __align__(16) float xlds[2][G3_][16];             // 96KB [buf][g][b_local]

  // zero h buffer 0 (8KB = 512 * 16B)
  ((int4*)&hlds[0][0][0][0])[tid] = int4{0, 0, 0, 0};

  // issue t=0 staging (drained by first __syncthreads in loop)
  {
    const char* lb = (const char*)&xlds[0][0][0];
#pragma unroll
    for (int j = 0; j < 6; ++j) {
      const int c = j * 512 + tid;
      async16(xp + (size_t)(c >> 2) * B_ + b0 + (c & 3) * 4,
              lb + (size_t)(j * 512 + wave * 64) * 16);
    }
  }

  // W_hh fragments (bf16) -> registers for all 128 steps
  bf16x8 wfg[2][3][8];
#pragma unroll
  for (int tt = 0; tt < 2; ++tt) {
    const int gbase = gb0 + tt * 16;
#pragma unroll
    for (int g = 0; g < 3; ++g) {
      const float* wrow = whh + (size_t)(g * H_ + gbase) * H_;
#pragma unroll
      for (int kk = 0; kk < 8; ++kk) {
        const float* p = wrow + kk * 32 + lg * 8;
        float4 w0 = *(const float4*)p;
        float4 w1 = *(const float4*)(p + 4);
        bf16x8 f;
        f[0] = f2bf(w0.x); f[1] = f2bf(w0.y); f[2] = f2bf(w0.z); f[3] = f2bf(w0.w);
        f[4] = f2bf(w1.x); f[5] = f2bf(w1.y); f[6] = f2bf(w1.z); f[7] = f2bf(w1.w);
        wfg[tt][g][kk] = f;
      }
    }
  }

  float bhn[2];
  bhn[0] = bhh[2 * H_ + gb0];
  bhn[1] = bhh[2 * H_ + gb0 + 16];

  int len_[4];
#pragma unroll
  for (int i = 0; i < 4; ++i) len_[i] = lens[b0 + lg * 4 + i];

  float hreg[2][4] = {};

  int p = 0;
  for (int t = 0; t < S_; ++t) {
    __syncthreads();            // drains vmcnt: xlds[t&1] complete; hlds[p] visible
    const int xb = t & 1;

    if (t + 1 < S_) {           // stage t+1 into the buffer last read at t-1
      const float* base = xp + (size_t)(t + 1) * G3_ * B_;
      const char* lb = (const char*)&xlds[xb ^ 1][0][0];
#pragma unroll
      for (int j = 0; j < 6; ++j) {
        const int c = j * 512 + tid;
        async16(base + (size_t)(c >> 2) * B_ + b0 + (c & 3) * 4,
                lb + (size_t)(j * 512 + wave * 64) * 16);
      }
    }

    const int s_out = dir ? (S_ - 1 - t) : t;

#pragma unroll
    for (int tt = 0; tt < 2; ++tt) {
      const int u = gb0 + tt * 16;
      f32x4 accr = *(const f32x4*)&xlds[xb][u][lg * 4];          // b_hh_r folded
      f32x4 accz = *(const f32x4*)&xlds[xb][H_ + u][lg * 4];     // b_hh_z folded
      f32x4 accn = f32x4{bhn[tt], bhn[tt], bhn[tt], bhn[tt]};
#pragma unroll
      for (int kk = 0; kk < 8; ++kk) {
        bf16x8 a = *(const bf16x8*)&hlds[p][kk * 4 + lg][col][0];
        accr = __builtin_amdgcn_mfma_f32_16x16x32_bf16(a, wfg[tt][0][kk], accr, 0, 0, 0);
        accz = __builtin_amdgcn_mfma_f32_16x16x32_bf16(a, wfg[tt][1][kk], accz, 0, 0, 0);
        accn = __builtin_amdgcn_mfma_f32_16x16x32_bf16(a, wfg[tt][2][kk], accn, 0, 0, 0);
      }
      f32x4 xn4 = *(const f32x4*)&xlds[xb][2 * H_ + u][lg * 4];
#pragma unroll
      for (int i = 0; i < 4; ++i) {
        const int bi = lg * 4 + i;
        float r  = 1.f / (1.f + __expf(-accr[i]));
        float z  = 1.f / (1.f + __expf(-accz[i]));
        float nx = xn4[i] + r * accn[i];
        float n  = 1.f - 2.f / (__expf(2.f * nx) + 1.f);
        float hn = n + z * (hreg[tt][i] - n);
        hreg[tt][i] = hn;
        out[((size_t)(b0 + bi) * S_ + s_out) * D2H_ + dir * H_ + u] =
            (s_out < len_[i]) ? hn : 0.f;
        hlds[p ^ 1][u >> 3][bi][u & 7] = (unsigned short)f2bf(hn);
      }
    }
    p ^= 1;
  }
}

// ---------------------------------------------------------------------------
// K3: proj[b,s,c] = out[b,s,:] . proj_w[c,:] + proj_b[c]   (fp32)
// ---------------------------------------------------------------------------
__global__ __launch_bounds__(256) void proj_gemm(
    const float* __restrict__ a, const float* __restrict__ w,
    const float* __restrict__ bias, float* __restrict__ proj)
{
  const int bm = blockIdx.x;
  const int n0 = blockIdx.y * 64;

  __shared__ float As[16][68];
  __shared__ float Bs[16][68];

  const int tid = threadIdx.x;
  const int row = tid >> 2;
  const int kq  = (tid & 3) << 2;
  const int tx  = tid & 15, ty = tid >> 4;

  const float* arow = a + (size_t)(bm * 64 + row) * D2H_ + kq;
  const float* brow = w + (size_t)(n0 + row) * D2H_ + kq;

  float acc[4][4] = {};

  for (int k0 = 0; k0 < D2H_; k0 += 16) {
    float4 av = *(const float4*)(arow + k0);
    float4 bv = *(const float4*)(brow + k0);
    As[kq + 0][row] = av.x; As[kq + 1][row] = av.y;
    As[kq + 2][row] = av.z; As[kq + 3][row] = av.w;
    Bs[kq + 0][row] = bv.x; Bs[kq + 1][row] = bv.y;
    Bs[kq + 2][row] = bv.z; Bs[kq + 3][row] = bv.w;
    __syncthreads();
#pragma unroll
    for (int k = 0; k < 16; ++k) {
      float4 av2 = *(const float4*)&As[k][ty * 4];
      float4 bv2 = *(const float4*)&Bs[k][tx * 4];
      acc[0][0] += av2.x * bv2.x; acc[0][1] += av2.x * bv2.y; acc[0][2] += av2.x * bv2.z; acc[0][3] += av2.x * bv2.w;
      acc[1][0] += av2.y * bv2.x; acc[1][1] += av2.y * bv2.y; acc[1][2] += av2.y * bv2.z; acc[1][3] += av2.y * bv2.w;
      acc[2][0] += av2.z * bv2.x; acc[2][1] += av2.z * bv2.y; acc[2][2] += av2.z * bv2.z; acc[2][3] += av2.z * bv2.w;
      acc[3][0] += av2.w * bv2.x; acc[3][1] += av2.w * bv2.y; acc[3][2] += av2.w * bv2.z; acc[3][3] += av2.w * bv2.w;
    }
    __syncthreads();
  }

  float4 bv4 = *(const float4*)(bias + n0 + tx * 4);
#pragma unroll
  for (int i = 0; i < 4; ++i) {
    int m = bm * 64 + ty * 4 + i;
    float4 o;
    o.x = acc[i][0] + bv4.x; o.y = acc[i][1] + bv4.y;
    o.z = acc[i][2] + bv4.z; o.w = acc[i][3] + bv4.w;
    *(float4*)(proj + (size_t)m * C_ + n0 + tx * 4) = o;
  }
}

// ---------------------------------------------------------------------------
__global__ __launch_bounds__(256) void bn_stats(
    const float* __restrict__ proj, float* __restrict__ mu, float* __restrict__ rstd)
{
  const int s = blockIdx.x, tid = threadIdx.x;
  float sum = 0.f, sq = 0.f;
  for (int b = 0; b < B_; ++b) {
    float v = proj[((size_t)b * S_ + s) * C_ + tid];
    sum += v; sq += v * v;
  }
#pragma unroll
  for (int o = 32; o; o >>= 1) { sum += __shfl_down(sum, o); sq += __shfl_down(sq, o); }
  __shared__ float r1[4], r2[4];
  const int lane = tid & 63, wid = tid >> 6;
  if (!lane) { r1[wid] = sum; r2[wid] = sq; }
  __syncthreads();
  if (!tid) {
    float s1 = r1[0] + r1[1] + r1[2] + r1[3];
    float s2 = r2[0] + r2[1] + r2[2] + r2[3];
    float m = s1 / (float)(B_ * C_);
    float var = s2 / (float)(B_ * C_) - m * m;
    mu[s] = m;
    rstd[s] = rsqrtf(var + 1e-5f);
  }
}

__global__ __launch_bounds__(256) void score_k(
    const float* __restrict__ proj, const float* __restrict__ mu,
    const float* __restrict__ rstd, const float* __restrict__ gamma,
    const float* __restrict__ beta, const float* __restrict__ ctx,
    float* __restrict__ scores)
{
  const int wid = threadIdx.x >> 6, lane = threadIdx.x & 63;
  const int m = blockIdx.x * 4 + wid;
  const int s = m & 127;
  float4 v  = *(const float4*)(proj + (size_t)m * C_ + lane * 4);
  float4 cv = *(const float4*)(ctx + lane * 4);
  const float ms = mu[s], rs = rstd[s], g = gamma[s], be = beta[s];
  float acc = fmaxf((v.x - ms) * rs * g + be, 0.f) * cv.x
            + fmaxf((v.y - ms) * rs * g + be, 0.f) * cv.y
            + fmaxf((v.z - ms) * rs * g + be, 0.f) * cv.z
            + fmaxf((v.w - ms) * rs * g + be, 0.f) * cv.w;
#pragma unroll
  for (int o = 32; o; o >>= 1) acc += __shfl_down(acc, o);
  if (!lane) scores[m] = acc;
}

__global__ __launch_bounds__(128) void softmax_k(
    const float* __restrict__ scores, float* __restrict__ attn)
{
  const int b = blockIdx.x, tid = threadIdx.x;
  float v = scores[b * S_ + tid];
  float mx = v;
#pragma unroll
  for (int o = 32; o; o >>= 1) mx = fmaxf(mx, __shfl_down(mx, o));
  __shared__ float t0[2], t1[2];
  const int lane = tid & 63, wid = tid >> 6;
  if (!lane) t0[wid] = mx;
  __syncthreads();
  mx = fmaxf(t0[0], t0[1]);
  float e = __expf(v - mx);
  float ssum = e;
#pragma unroll
  for (int o = 32; o; o >>= 1) ssum += __shfl_down(ssum, o);
  if (!lane) t1[wid] = ssum;
  __syncthreads();
  attn[b * S_ + tid] = e / (t1[0] + t1[1]);
}

__global__ __launch_bounds__(512) void final_k(
    const float* __restrict__ attn, const float* __restrict__ out,
    float* __restrict__ y)
{
  const int b = blockIdx.x, d = threadIdx.x;
  __shared__ float a[S_];
  if (threadIdx.x < S_) a[threadIdx.x] = attn[b * S_ + threadIdx.x];
  __syncthreads();
  float acc = 0.f;
  for (int s = 0; s < S_; ++s)
    acc += a[s] * out[((size_t)b * S_ + s) * D2H_ + d];
  y[(size_t)b * D2H_ + d] = acc;
}

// ---------------------------------------------------------------------------
extern "C" void kernel_launch(void* const* d_in, const int* in_sizes, int n_in,
                              void* d_out, int out_size, void* d_ws, size_t ws_size,
                              hipStream_t stream)
{
  const float* x      = (const float*)d_in[0];
  const int*   lens   = (const int*)d_in[2];
  const float* w_ih_f = (const float*)d_in[3];
  const float* w_hh_f = (const float*)d_in[4];
  const float* b_ih_f = (const float*)d_in[5];
  const float* b_hh_f = (const float*)d_in[6];
  const float* w_ih_b = (const float*)d_in[7];
  const float* w_hh_b = (const float*)d_in[8];
  const float* b_ih_b = (const float*)d_in[9];
  const float* b_hh_b = (const float*)d_in[10];
  const float* proj_w = (const float*)d_in[11];
  const float* proj_b = (const float*)d_in[12];
  const float* gamma  = (const float*)d_in[13];
  const float* beta   = (const float*)d_in[14];
  const float* ctx    = (const float*)d_in[15];

  float* ws = (float*)d_ws;
  // 128 MiB total (same footprint as prior rounds):
  float* outm = ws;                       //  8,388,608 f
  float* xpf  = ws + 8388608;             // 12,582,912 f  [t][g][b]
  float* xpb  = ws + 20971520;            // 12,582,912 f
  // epilogue aliases (xpf dead after gru):
  float* proj   = ws + 8388608;           //  4,194,304 f
  float* mu     = ws + 12582912;          //  128
  float* rstd   = ws + 12583040;          //  128
  float* scores = ws + 12583168;          //  16,384
  float* attn   = ws + 12599552;          //  16,384

  xp_gemm_bf<<<dim3(128, 12), 256, 0, stream>>>(
      x, w_ih_f, w_ih_b, b_ih_f, b_hh_f, b_ih_b, b_hh_b, xpf, xpb);
  gru_mfma<<<16, 512, 0, stream>>>(xpf, xpb, w_hh_f, w_hh_b, b_hh_f, b_hh_b, lens, outm);
  proj_gemm<<<dim3(256, 4), 256, 0, stream>>>(outm, proj_w, proj_b, proj);
  bn_stats<<<128, 256, 0, stream>>>(proj, mu, rstd);
  score_k<<<4096, 256, 0, stream>>>(proj, mu, rstd, gamma, beta, ctx, scores);
  softmax_k<<<128, 128, 0, stream>>>(scores, attn);
  final_k<<<128, 512, 0, stream>>>(attn, outm, (float*)d_out);
}

// Round 4
// 547.958 us; speedup vs baseline: 6.1843x; 1.1783x over previous
//
#include <hip/hip_runtime.h>
#include <hip/hip_bf16.h>

#define B_   128
#define S_   128
#define IN_  512
#define H_   256
#define G3_  768   // 3*H
#define C_   256
#define D2H_ 512   // 2*H
#define XPAD 20    // padded b-dim of xp tiles (16 used + 4 pad) -> bank-conflict-free

typedef short bf16x8 __attribute__((ext_vector_type(8)));
typedef float f32x4  __attribute__((ext_vector_type(4)));

static __device__ __forceinline__ short f2bf(float f) {
  unsigned u = __float_as_uint(f);
  return (short)((u + 0x7fffu + ((u >> 16) & 1u)) >> 16);
}
static __device__ __forceinline__ float bf2f(unsigned short v) {
  return __uint_as_float((unsigned)v << 16);
}

// async global->LDS, 16B per lane. LDS dest is wave-uniform base (+lane*16 in HW).
static __device__ __forceinline__ void async16(const void* g, const void* l) {
  __builtin_amdgcn_global_load_lds(
      (const __attribute__((address_space(1))) void*)g,
      (__attribute__((address_space(3))) void*)l, 16, 0, 0);
}

// ---------------------------------------------------------------------------
// K1: xp = bf16( x @ w_ih^T + b_ih (+ b_hh for r,z) ), both dirs.
// Output layout: xp[t][grp=b/16][g][XPAD]  (bf16, b%16 in last dim, 4 pad)
// Per (t,grp) slice = 768*20*2B = 30720B contiguous -> gru stages it linearly.
// Grid (128, 12): x = s, y<6 fwd cols, y>=6 bwd cols.
// ---------------------------------------------------------------------------
__global__ __launch_bounds__(256) void xp_gemm_bf(
    const float* __restrict__ x,
    const float* __restrict__ wf, const float* __restrict__ wb,
    const float* __restrict__ bif, const float* __restrict__ bhf,
    const float* __restrict__ bib, const float* __restrict__ bhb,
    unsigned short* __restrict__ xpf, unsigned short* __restrict__ xpb)
{
  const int sb = blockIdx.x;                 // s = 0..127
  const int bn = blockIdx.y;                 // 0..11
  const bool fwd = (bn < 6);
  const float* __restrict__ wsrc = fwd ? wf : wb;
  const float* __restrict__ bi   = fwd ? bif : bib;
  const float* __restrict__ bh   = fwd ? bhf : bhb;
  const int nloc0 = (fwd ? bn : bn - 6) * 128;   // col base within dir

  __shared__ __align__(16) unsigned short As[128][56];
  __shared__ __align__(16) unsigned short Bs[128][56];

  const int tid  = threadIdx.x;
  const int wave = tid >> 6, lane = tid & 63;
  const int col  = lane & 15, lg = lane >> 4;
  const int wm   = wave >> 1, wn = wave & 1;
  const int rr   = tid >> 1;                 // staging row 0..127
  const int hf   = (tid & 1) * 16;           // staging elem offset 0/16

  const float* ax = x    + ((size_t)(rr * 128 + sb) * IN_ + hf);
  const float* bx = wsrc + ((size_t)(nloc0 + rr) * IN_ + hf);

  f32x4 acc[4][4];
#pragma unroll
  for (int i = 0; i < 4; ++i)
#pragma unroll
    for (int j = 0; j < 4; ++j) acc[i][j] = f32x4{0.f, 0.f, 0.f, 0.f};

  for (int k0 = 0; k0 < IN_; k0 += 32) {
    float4 a0 = *(const float4*)(ax + k0);
    float4 a1 = *(const float4*)(ax + k0 + 4);
    float4 a2 = *(const float4*)(ax + k0 + 8);
    float4 a3 = *(const float4*)(ax + k0 + 12);
    float4 c0 = *(const float4*)(bx + k0);
    float4 c1 = *(const float4*)(bx + k0 + 4);
    float4 c2 = *(const float4*)(bx + k0 + 8);
    float4 c3 = *(const float4*)(bx + k0 + 12);
    __syncthreads();
    {
      bf16x8 p0, p1;
      p0[0]=f2bf(a0.x); p0[1]=f2bf(a0.y); p0[2]=f2bf(a0.z); p0[3]=f2bf(a0.w);
      p0[4]=f2bf(a1.x); p0[5]=f2bf(a1.y); p0[6]=f2bf(a1.z); p0[7]=f2bf(a1.w);
      p1[0]=f2bf(a2.x); p1[1]=f2bf(a2.y); p1[2]=f2bf(a2.z); p1[3]=f2bf(a2.w);
      p1[4]=f2bf(a3.x); p1[5]=f2bf(a3.y); p1[6]=f2bf(a3.z); p1[7]=f2bf(a3.w);
      *(bf16x8*)&As[rr][hf]     = p0;
      *(bf16x8*)&As[rr][hf + 8] = p1;
      p0[0]=f2bf(c0.x); p0[1]=f2bf(c0.y); p0[2]=f2bf(c0.z); p0[3]=f2bf(c0.w);
      p0[4]=f2bf(c1.x); p0[5]=f2bf(c1.y); p0[6]=f2bf(c1.z); p0[7]=f2bf(c1.w);
      p1[0]=f2bf(c2.x); p1[1]=f2bf(c2.y); p1[2]=f2bf(c2.z); p1[3]=f2bf(c2.w);
      p1[4]=f2bf(c3.x); p1[5]=f2bf(c3.y); p1[6]=f2bf(c3.z); p1[7]=f2bf(c3.w);
      *(bf16x8*)&Bs[rr][hf]     = p0;
      *(bf16x8*)&Bs[rr][hf + 8] = p1;
    }
    __syncthreads();
    bf16x8 af[4], bf_[4];
#pragma unroll
    for (int mi = 0; mi < 4; ++mi)
      af[mi] = *(const bf16x8*)&As[wm * 64 + mi * 16 + col][lg * 8];
#pragma unroll
    for (int ni = 0; ni < 4; ++ni)
      bf_[ni] = *(const bf16x8*)&Bs[wn * 64 + ni * 16 + col][lg * 8];
#pragma unroll
    for (int mi = 0; mi < 4; ++mi)
#pragma unroll
      for (int ni = 0; ni < 4; ++ni)
        acc[mi][ni] = __builtin_amdgcn_mfma_f32_16x16x32_bf16(af[mi], bf_[ni], acc[mi][ni], 0, 0, 0);
  }

  // epilogue: bias fold, bf16 pack, [t][grp][g][XPAD] store (8B per (mi,ni))
  const int t = fwd ? sb : (S_ - 1 - sb);
  unsigned short* __restrict__ dstbase = fwd ? xpf : xpb;
#pragma unroll
  for (int ni = 0; ni < 4; ++ni) {
    const int g = nloc0 + wn * 64 + ni * 16 + col;       // 0..767 within dir
    const float bias = bi[g] + (g < 2 * H_ ? bh[g] : 0.f);
#pragma unroll
    for (int mi = 0; mi < 4; ++mi) {
      const int grp = wm * 4 + mi;                       // b/16
      ushort4 o;
      o.x = (unsigned short)f2bf(acc[mi][ni][0] + bias);
      o.y = (unsigned short)f2bf(acc[mi][ni][1] + bias);
      o.z = (unsigned short)f2bf(acc[mi][ni][2] + bias);
      o.w = (unsigned short)f2bf(acc[mi][ni][3] + bias);
      *(ushort4*)(dstbase + (((size_t)t * 8 + grp) * G3_ + g) * XPAD + lg * 4) = o;
    }
  }
}

// ---------------------------------------------------------------------------
// K2: GRU recurrence, MFMA, W_hh register-resident, xp bf16 LDS-staged.
// 16 blocks = 2 dirs x 8 groups of 16 batches; 512 threads = 8 waves.
// Per-step stage = one contiguous 30720B slice via global_load_lds (dbuf,
// issued right after the barrier; next barrier's vmcnt drain completes it).
// ---------------------------------------------------------------------------
__global__ __launch_bounds__(512, 2) void gru_mfma(
    const unsigned short* __restrict__ xpf, const unsigned short* __restrict__ xpb,
    const float* __restrict__ whf, const float* __restrict__ whb,
    const float* __restrict__ bhf, const float* __restrict__ bhb,
    const int* __restrict__ lens, float* __restrict__ out)
{
  const int dir = blockIdx.x >> 3;
  const int grp = blockIdx.x & 7;
  const int b0  = grp * 16;
  const unsigned short* __restrict__ xp = dir ? xpb : xpf;
  const float* __restrict__ whh = dir ? whb : whf;
  const float* __restrict__ bhh = dir ? bhb : bhf;

  const int tid  = threadIdx.x;
  const int wave = tid >> 6;
  const int lane = tid & 63;
  const int col  = lane & 15;
  const int lg   = lane >> 4;
  const int gb0  = wave * 32 + col;

  __shared__ __align__(16) unsigned short hlds[2][32][16][8];   // 16KB
  __shared__ __align__(16) unsigned short xlds[2][G3_ * XPAD];  // 60KB

  // zero h buffer 0 (8KB = 512*16B)
  ((int4*)&hlds[0][0][0][0])[tid] = int4{0, 0, 0, 0};

  // stage t=0 (1920 granules of 16B; waves 6,7 idle at j=3)
  {
    const unsigned short* base = xp + (size_t)grp * (G3_ * XPAD);
    const char* lb = (const char*)&xlds[0][0];
#pragma unroll
    for (int j = 0; j < 4; ++j) {
      const int c = j * 512 + tid;
      if (c < 1920)
        async16(base + (size_t)c * 8, lb + (size_t)(j * 512 + wave * 64) * 16);
    }
  }

  // W_hh fragments (bf16) -> registers for all 128 steps
  bf16x8 wfg[2][3][8];
#pragma unroll
  for (int tt = 0; tt < 2; ++tt) {
    const int gbase = gb0 + tt * 16;
#pragma unroll
    for (int g = 0; g < 3; ++g) {
      const float* wrow = whh + (size_t)(g * H_ + gbase) * H_;
#pragma unroll
      for (int kk = 0; kk < 8; ++kk) {
        const float* p = wrow + kk * 32 + lg * 8;
        float4 w0 = *(const float4*)p;
        float4 w1 = *(const float4*)(p + 4);
        bf16x8 f;
        f[0] = f2bf(w0.x); f[1] = f2bf(w0.y); f[2] = f2bf(w0.z); f[3] = f2bf(w0.w);
        f[4] = f2bf(w1.x); f[5] = f2bf(w1.y); f[6] = f2bf(w1.z); f[7] = f2bf(w1.w);
        wfg[tt][g][kk] = f;
      }
    }
  }

  float bhn[2];
  bhn[0] = bhh[2 * H_ + gb0];
  bhn[1] = bhh[2 * H_ + gb0 + 16];

  int len_[4];
#pragma unroll
  for (int i = 0; i < 4; ++i) len_[i] = lens[b0 + lg * 4 + i];

  float hreg[2][4] = {};

  int p = 0;
  for (int t = 0; t < S_; ++t) {
    __syncthreads();            // drains vmcnt: xlds[t&1] staged; hlds[p] visible
    const int xb = t & 1;

    if (t + 1 < S_) {           // stage t+1 into the other buffer
      const unsigned short* base = xp + ((size_t)(t + 1) * 8 + grp) * (G3_ * XPAD);
      const char* lb = (const char*)&xlds[xb ^ 1][0];
#pragma unroll
      for (int j = 0; j < 4; ++j) {
        const int c = j * 512 + tid;
        if (c < 1920)
          async16(base + (size_t)c * 8, lb + (size_t)(j * 512 + wave * 64) * 16);
      }
    }

    const int s_out = dir ? (S_ - 1 - t) : t;

#pragma unroll
    for (int tt = 0; tt < 2; ++tt) {
      const int u = gb0 + tt * 16;
      ushort4 r4 = *(const ushort4*)&xlds[xb][(size_t)u * XPAD + lg * 4];
      ushort4 z4 = *(const ushort4*)&xlds[xb][(size_t)(H_ + u) * XPAD + lg * 4];
      f32x4 accr, accz, accn;
      accr[0] = bf2f(r4.x); accr[1] = bf2f(r4.y); accr[2] = bf2f(r4.z); accr[3] = bf2f(r4.w);
      accz[0] = bf2f(z4.x); accz[1] = bf2f(z4.y); accz[2] = bf2f(z4.z); accz[3] = bf2f(z4.w);
      accn = f32x4{bhn[tt], bhn[tt], bhn[tt], bhn[tt]};
#pragma unroll
      for (int kk = 0; kk < 8; ++kk) {
        bf16x8 a = *(const bf16x8*)&hlds[p][kk * 4 + lg][col][0];
        accr = __builtin_amdgcn_mfma_f32_16x16x32_bf16(a, wfg[tt][0][kk], accr, 0, 0, 0);
        accz = __builtin_amdgcn_mfma_f32_16x16x32_bf16(a, wfg[tt][1][kk], accz, 0, 0, 0);
        accn = __builtin_amdgcn_mfma_f32_16x16x32_bf16(a, wfg[tt][2][kk], accn, 0, 0, 0);
      }
      ushort4 n4 = *(const ushort4*)&xlds[xb][(size_t)(2 * H_ + u) * XPAD + lg * 4];
#pragma unroll
      for (int i = 0; i < 4; ++i) {
        const int bi = lg * 4 + i;
        float r  = 1.f / (1.f + __expf(-accr[i]));
        float z  = 1.f / (1.f + __expf(-accz[i]));
        float nx = bf2f((&n4.x)[i]) + r * accn[i];
        float n  = 1.f - 2.f / (__expf(2.f * nx) + 1.f);
        float hn = n + z * (hreg[tt][i] - n);
        hreg[tt][i] = hn;
        out[((size_t)(b0 + bi) * S_ + s_out) * D2H_ + dir * H_ + u] =
            (s_out < len_[i]) ? hn : 0.f;
        hlds[p ^ 1][u >> 3][bi][u & 7] = (unsigned short)f2bf(hn);
      }
    }
    p ^= 1;
  }
}

// ---------------------------------------------------------------------------
// K3: proj[b,s,c] = out[b,s,:] . proj_w[c,:] + proj_b[c]   (fp32)
// ---------------------------------------------------------------------------
__global__ __launch_bounds__(256) void proj_gemm(
    const float* __restrict__ a, const float* __restrict__ w,
    const float* __restrict__ bias, float* __restrict__ proj)
{
  const int bm = blockIdx.x;
  const int n0 = blockIdx.y * 64;

  __shared__ float As[16][68];
  __shared__ float Bs[16][68];

  const int tid = threadIdx.x;
  const int row = tid >> 2;
  const int kq  = (tid & 3) << 2;
  const int tx  = tid & 15, ty = tid >> 4;

  const float* arow = a + (size_t)(bm * 64 + row) * D2H_ + kq;
  const float* brow = w + (size_t)(n0 + row) * D2H_ + kq;

  float acc[4][4] = {};

  for (int k0 = 0; k0 < D2H_; k0 += 16) {
    float4 av = *(const float4*)(arow + k0);
    float4 bv = *(const float4*)(brow + k0);
    As[kq + 0][row] = av.x; As[kq + 1][row] = av.y;
    As[kq + 2][row] = av.z; As[kq + 3][row] = av.w;
    Bs[kq + 0][row] = bv.x; Bs[kq + 1][row] = bv.y;
    Bs[kq + 2][row] = bv.z; Bs[kq + 3][row] = bv.w;
    __syncthreads();
#pragma unroll
    for (int k = 0; k < 16; ++k) {
      float4 av2 = *(const float4*)&As[k][ty * 4];
      float4 bv2 = *(const float4*)&Bs[k][tx * 4];
      acc[0][0] += av2.x * bv2.x; acc[0][1] += av2.x * bv2.y; acc[0][2] += av2.x * bv2.z; acc[0][3] += av2.x * bv2.w;
      acc[1][0] += av2.y * bv2.x; acc[1][1] += av2.y * bv2.y; acc[1][2] += av2.y * bv2.z; acc[1][3] += av2.y * bv2.w;
      acc[2][0] += av2.z * bv2.x; acc[2][1] += av2.z * bv2.y; acc[2][2] += av2.z * bv2.z; acc[2][3] += av2.z * bv2.w;
      acc[3][0] += av2.w * bv2.x; acc[3][1] += av2.w * bv2.y; acc[3][2] += av2.w * bv2.z; acc[3][3] += av2.w * bv2.w;
    }
    __syncthreads();
  }

  float4 bv4 = *(const float4*)(bias + n0 + tx * 4);
#pragma unroll
  for (int i = 0; i < 4; ++i) {
    int m = bm * 64 + ty * 4 + i;
    float4 o;
    o.x = acc[i][0] + bv4.x; o.y = acc[i][1] + bv4.y;
    o.z = acc[i][2] + bv4.z; o.w = acc[i][3] + bv4.w;
    *(float4*)(proj + (size_t)m * C_ + n0 + tx * 4) = o;
  }
}

// ---------------------------------------------------------------------------
__global__ __launch_bounds__(256) void bn_stats(
    const float* __restrict__ proj, float* __restrict__ mu, float* __restrict__ rstd)
{
  const int s = blockIdx.x, tid = threadIdx.x;
  float sum = 0.f, sq = 0.f;
  for (int b = 0; b < B_; ++b) {
    float v = proj[((size_t)b * S_ + s) * C_ + tid];
    sum += v; sq += v * v;
  }
#pragma unroll
  for (int o = 32; o; o >>= 1) { sum += __shfl_down(sum, o); sq += __shfl_down(sq, o); }
  __shared__ float r1[4], r2[4];
  const int lane = tid & 63, wid = tid >> 6;
  if (!lane) { r1[wid] = sum; r2[wid] = sq; }
  __syncthreads();
  if (!tid) {
    float s1 = r1[0] + r1[1] + r1[2] + r1[3];
    float s2 = r2[0] + r2[1] + r2[2] + r2[3];
    float m = s1 / (float)(B_ * C_);
    float var = s2 / (float)(B_ * C_) - m * m;
    mu[s] = m;
    rstd[s] = rsqrtf(var + 1e-5f);
  }
}

__global__ __launch_bounds__(256) void score_k(
    const float* __restrict__ proj, const float* __restrict__ mu,
    const float* __restrict__ rstd, const float* __restrict__ gamma,
    const float* __restrict__ beta, const float* __restrict__ ctx,
    float* __restrict__ scores)
{
  const int wid = threadIdx.x >> 6, lane = threadIdx.x & 63;
  const int m = blockIdx.x * 4 + wid;
  const int s = m & 127;
  float4 v  = *(const float4*)(proj + (size_t)m * C_ + lane * 4);
  float4 cv = *(const float4*)(ctx + lane * 4);
  const float ms = mu[s], rs = rstd[s], g = gamma[s], be = beta[s];
  float acc = fmaxf((v.x - ms) * rs * g + be, 0.f) * cv.x
            + fmaxf((v.y - ms) * rs * g + be, 0.f) * cv.y
            + fmaxf((v.z - ms) * rs * g + be, 0.f) * cv.z
            + fmaxf((v.w - ms) * rs * g + be, 0.f) * cv.w;
#pragma unroll
  for (int o = 32; o; o >>= 1) acc += __shfl_down(acc, o);
  if (!lane) scores[m] = acc;
}

__global__ __launch_bounds__(128) void softmax_k(
    const float* __restrict__ scores, float* __restrict__ attn)
{
  const int b = blockIdx.x, tid = threadIdx.x;
  float v = scores[b * S_ + tid];
  float mx = v;
#pragma unroll
  for (int o = 32; o; o >>= 1) mx = fmaxf(mx, __shfl_down(mx, o));
  __shared__ float t0[2], t1[2];
  const int lane = tid & 63, wid = tid >> 6;
  if (!lane) t0[wid] = mx;
  __syncthreads();
  mx = fmaxf(t0[0], t0[1]);
  float e = __expf(v - mx);
  float ssum = e;
#pragma unroll
  for (int o = 32; o; o >>= 1) ssum += __shfl_down(ssum, o);
  if (!lane) t1[wid] = ssum;
  __syncthreads();
  attn[b * S_ + tid] = e / (t1[0] + t1[1]);
}

__global__ __launch_bounds__(512) void final_k(
    const float* __restrict__ attn, const float* __restrict__ out,
    float* __restrict__ y)
{
  const int b = blockIdx.x, d = threadIdx.x;
  __shared__ float a[S_];
  if (threadIdx.x < S_) a[threadIdx.x] = attn[b * S_ + threadIdx.x];
  __syncthreads();
  float acc = 0.f;
  for (int s = 0; s < S_; ++s)
    acc += a[s] * out[((size_t)b * S_ + s) * D2H_ + d];
  y[(size_t)b * D2H_ + d] = acc;
}

// ---------------------------------------------------------------------------
extern "C" void kernel_launch(void* const* d_in, const int* in_sizes, int n_in,
                              void* d_out, int out_size, void* d_ws, size_t ws_size,
                              hipStream_t stream)
{
  const float* x      = (const float*)d_in[0];
  const int*   lens   = (const int*)d_in[2];
  const float* w_ih_f = (const float*)d_in[3];
  const float* w_hh_f = (const float*)d_in[4];
  const float* b_ih_f = (const float*)d_in[5];
  const float* b_hh_f = (const float*)d_in[6];
  const float* w_ih_b = (const float*)d_in[7];
  const float* w_hh_b = (const float*)d_in[8];
  const float* b_ih_b = (const float*)d_in[9];
  const float* b_hh_b = (const float*)d_in[10];
  const float* proj_w = (const float*)d_in[11];
  const float* proj_b = (const float*)d_in[12];
  const float* gamma  = (const float*)d_in[13];
  const float* beta   = (const float*)d_in[14];
  const float* ctx    = (const float*)d_in[15];

  float* ws = (float*)d_ws;
  // outm 32MB | xpf 31.5MB | xpb 31.5MB  (bf16 xp, padded)
  float* outm = ws;                                        //  8,388,608 f
  unsigned short* xpf = (unsigned short*)(ws + 8388608);   // 15,728,640 us
  unsigned short* xpb = xpf + 15728640;                    // 15,728,640 us
  // epilogue aliases (xp dead after gru):
  float* proj   = ws + 8388608;                            //  4,194,304 f
  float* mu     = ws + 12582912;
  float* rstd   = ws + 12583040;
  float* scores = ws + 12583168;
  float* attn   = ws + 12599552;

  xp_gemm_bf<<<dim3(128, 12), 256, 0, stream>>>(
      x, w_ih_f, w_ih_b, b_ih_f, b_hh_f, b_ih_b, b_hh_b, xpf, xpb);
  gru_mfma<<<16, 512, 0, stream>>>(xpf, xpb, w_hh_f, w_hh_b, b_hh_f, b_hh_b, lens, outm);
  proj_gemm<<<dim3(256, 4), 256, 0, stream>>>(outm, proj_w, proj_b, proj);
  bn_stats<<<128, 256, 0, stream>>>(proj, mu, rstd);
  score_k<<<4096, 256, 0, stream>>>(proj, mu, rstd, gamma, beta, ctx, scores);
  softmax_k<<<128, 128, 0, stream>>>(scores, attn);
  final_k<<<128, 512, 0, stream>>>(attn, outm, (float*)d_out);
}